// Round 1
// baseline (573.859 us; speedup 1.0000x reference)
//
#include <hip/hip_runtime.h>

// ---------------------------------------------------------------------------
// R4: depth-1 double-buffered pipeline in all MFMA GEMMs (T3 minimal 2-phase):
//     per iter: issue next-tile glds16/gathers into buf^1, ds_read+MFMA from
//     buf, reg->LDS converts write-late (T14), ONE __syncthreads per iter.
//     Previously stage->drain->use exposed full load latency every K-step
//     (MfmaUtil 6.9%, HBM 14%: latency-bound, not pipe-bound).
//     feat kernel: ii/jj LDS dropped (direct per-thread index load) to fit
//     the 4-array double buffer in exactly 64KB.
// Carried from R3: hierarchical scan CSR, fused conv in encoder, fused
// LN / L2norm / logits epilogues, single-read feat.
// ---------------------------------------------------------------------------

#define NODES 50000
#define EDGES 300000
#define PAIRS 200000
#define SCAN_BLK 49  // ceil(NODES/1024)

typedef __attribute__((ext_vector_type(8))) short short8;
typedef __attribute__((ext_vector_type(4))) float f32x4;

__device__ __forceinline__ unsigned short f2bf(float f) {
  unsigned int u = __float_as_uint(f);
  u += 0x7fff + ((u >> 16) & 1);
  return (unsigned short)(u >> 16);
}
__device__ __forceinline__ float bf2f(unsigned short h) {
  return __uint_as_float(((unsigned int)h) << 16);
}

__device__ __forceinline__ void glds16(const void* g, void* l) {
  __builtin_amdgcn_global_load_lds(
      (const __attribute__((address_space(1))) unsigned int*)g,
      (__attribute__((address_space(3))) unsigned int*)l, 16, 0, 0);
}

// ---------------- CSR build ----------------

__global__ __launch_bounds__(256) void count_deg_kernel(const int* __restrict__ dst,
                                                        int* __restrict__ cnt) {
  int e = blockIdx.x * 256 + threadIdx.x;
  if (e < EDGES) atomicAdd(&cnt[dst[e]], 1);
}

__global__ __launch_bounds__(256) void blocksum_kernel(const int* __restrict__ cnt,
                                                       int* __restrict__ bsum) {
  int base = blockIdx.x * 1024 + threadIdx.x * 4;
  int s = 0;
  if (base + 3 < NODES) {
    int4 v = *(const int4*)(cnt + base);
    s = v.x + v.y + v.z + v.w;
  } else {
#pragma unroll
    for (int k = 0; k < 4; ++k)
      if (base + k < NODES) s += cnt[base + k];
  }
#pragma unroll
  for (int off = 32; off; off >>= 1) s += __shfl_down(s, off);
  __shared__ int ws[4];
  if ((threadIdx.x & 63) == 0) ws[threadIdx.x >> 6] = s;
  __syncthreads();
  if (threadIdx.x == 0) bsum[blockIdx.x] = ws[0] + ws[1] + ws[2] + ws[3];
}

__global__ __launch_bounds__(64) void scan_bsum_kernel(const int* __restrict__ bsum,
                                                       int* __restrict__ boff) {
  int lane = threadIdx.x;
  int v = (lane < SCAN_BLK) ? bsum[lane] : 0;
  int incl = v;
#pragma unroll
  for (int off = 1; off < 64; off <<= 1) {
    int t = __shfl_up(incl, off);
    if (lane >= off) incl += t;
  }
  if (lane < SCAN_BLK) boff[lane] = incl - v;
}

__global__ __launch_bounds__(256) void scan_final_kernel(const int* __restrict__ cnt,
                                                         const int* __restrict__ boff,
                                                         int* __restrict__ row_start,
                                                         float* __restrict__ degf) {
  int base = blockIdx.x * 1024 + threadIdx.x * 4;
  int c[4] = {0, 0, 0, 0};
  if (base + 3 < NODES) {
    int4 v = *(const int4*)(cnt + base);
    c[0] = v.x; c[1] = v.y; c[2] = v.z; c[3] = v.w;
  } else {
#pragma unroll
    for (int k = 0; k < 4; ++k)
      if (base + k < NODES) c[k] = cnt[base + k];
  }
  int s = c[0] + c[1] + c[2] + c[3];
  int lane = threadIdx.x & 63, wv = threadIdx.x >> 6;
  int incl = s;
#pragma unroll
  for (int off = 1; off < 64; off <<= 1) {
    int t = __shfl_up(incl, off);
    if (lane >= off) incl += t;
  }
  __shared__ int wsum[4];
  if (lane == 63) wsum[wv] = incl;
  __syncthreads();
  int wbase = 0;
  for (int k = 0; k < wv; ++k) wbase += wsum[k];
  int rs = boff[blockIdx.x] + wbase + incl - s;
#pragma unroll
  for (int k = 0; k < 4; ++k) {
    int i = base + k;
    if (i < NODES) {
      row_start[i] = rs;
      degf[i] = (float)(c[k] > 0 ? c[k] : 1);
      rs += c[k];
    }
  }
  if (blockIdx.x == 0 && threadIdx.x == 0) row_start[NODES] = EDGES;
}

__global__ __launch_bounds__(256) void fill_csr_kernel(const int* __restrict__ src,
                                                       const int* __restrict__ dst,
                                                       const int* __restrict__ row_start,
                                                       int* __restrict__ cursor,
                                                       int* __restrict__ csr) {
  int e = blockIdx.x * 256 + threadIdx.x;
  if (e < EDGES) {
    int d = dst[e];
    int pos = atomicAdd(&cursor[d], 1);
    csr[row_start[d] + pos] = src[e];
  }
}

// ---------------- weight transpose+convert ----------------

__global__ __launch_bounds__(256) void tconv_kernel(const float* __restrict__ in,
                                                    unsigned short* __restrict__ out,
                                                    int R, int C) {
  const float* inb = in + (size_t)blockIdx.z * R * C;
  unsigned short* outb = out + (size_t)blockIdx.z * R * C;
  __shared__ float t[32][33];
  int bx = blockIdx.x * 32, by = blockIdx.y * 32;
  int tx = threadIdx.x & 31, ty = threadIdx.x >> 5;
#pragma unroll
  for (int i = ty; i < 32; i += 8) t[i][tx] = inb[(size_t)(by + i) * C + bx + tx];
  __syncthreads();
#pragma unroll
  for (int i = ty; i < 32; i += 8)
    outb[(size_t)(bx + i) * R + by + tx] = f2bf(t[tx][i]);
}

// ---------------- fused MFMA GEMM, N=256, BM=64, double-buffered -----------
// F32A: A read as fp32 with in-register bf16 convert (encoder; K=480)
// EPI: 0 = relu->bf16; 1 = relu+LN->bf16; 2 = relu+LN+L2norm->f32+bf16
template <int DUAL, int EPI, int F32A>
__global__ __launch_bounds__(256) void mfma_fused(
    const unsigned short* __restrict__ A, const float* __restrict__ Af,
    const unsigned short* __restrict__ Bt,
    const unsigned short* __restrict__ A2, const unsigned short* __restrict__ B2t,
    const float* __restrict__ bias1, const float* __restrict__ bias2,
    const float* __restrict__ gamma, const float* __restrict__ beta,
    unsigned short* __restrict__ Cb, float* __restrict__ Cf, int M, int K) {
  __shared__ __attribute__((aligned(16))) unsigned short sm[2][320 * 32];  // 40KB
  __shared__ float red1[4][64], red2[4][64];
  __shared__ float mu_s[64], rs_s[64];
  const int tid = threadIdx.x;
  const int wv = tid >> 6, ln = tid & 63;
  const int lane15 = ln & 15, quad = ln >> 4;
  const int bm = blockIdx.x * 64;
  f32x4 acc[4][4] = {};

  const int ksteps = K >> 5;
  const int NS = ksteps * (DUAL + 1);

  // bf16-A staging: A(64x32) + B(256x32) via 5 glds16
  auto stage_bf16 = [&](int buf, int s) {
    int pass = 0, k0;
    if (DUAL && s >= ksteps) { pass = 1; k0 = (s - ksteps) * 32; }
    else { k0 = s * 32; }
    const unsigned short* __restrict__ Ap = pass ? A2 : A;
    const unsigned short* __restrict__ Bp = pass ? B2t : Bt;
#pragma unroll
    for (int q = 0; q < 5; ++q) {
      int L = q * 256 + tid;
      int r = L >> 2, ck = (L & 3) * 8;
      const unsigned short* gp;
      if (r < 64) {
        int gr = bm + r;
        if (gr > M - 1) gr = M - 1;
        gp = Ap + (size_t)gr * K + k0 + ck;
      } else {
        gp = Bp + (size_t)(r - 64) * K + k0 + ck;
      }
      glds16(gp, sm[buf] + (size_t)(q * 256 + (tid & 192)) * 8);
    }
  };
  // F32A: B-only staging (4 glds16); A handled via reg convert
  auto stage_B_f32a = [&](int buf, int k0) {
#pragma unroll
    for (int q = 1; q < 5; ++q) {
      int L = q * 256 + tid;
      int rr = L >> 2, ck = (L & 3) * 8;
      glds16(Bt + (size_t)(rr - 64) * K + k0 + ck,
             sm[buf] + (size_t)(q * 256 + (tid & 192)) * 8);
    }
  };

  const int ar_ = tid >> 2, aks = (tid & 3) * 8;
  int agr = bm + ar_;
  if (agr > M - 1) agr = M - 1;
  const float* aRow = F32A ? (Af + (size_t)agr * K) : nullptr;

  // prologue: stage step 0 into buf 0
  if (F32A) {
    float4 f0 = *(const float4*)(aRow + aks);
    float4 f1 = *(const float4*)(aRow + aks + 4);
    stage_B_f32a(0, 0);
    __attribute__((aligned(16))) unsigned short o[8] = {
        f2bf(f0.x), f2bf(f0.y), f2bf(f0.z), f2bf(f0.w),
        f2bf(f1.x), f2bf(f1.y), f2bf(f1.z), f2bf(f1.w)};
    *(short8*)&sm[0][ar_ * 32 + aks] = *(short8*)&o[0];
  } else {
    stage_bf16(0, 0);
  }
  __syncthreads();

  int cur = 0;
  for (int s = 0; s < NS; ++s) {
    const int nb = cur ^ 1;
    const bool has_next = (s + 1 < NS);
    float4 nf0, nf1;
    if (has_next) {
      if (F32A) {
        int k0n = (s + 1) * 32;
        nf0 = *(const float4*)(aRow + k0n + aks);
        nf1 = *(const float4*)(aRow + k0n + aks + 4);
        stage_B_f32a(nb, k0n);
      } else {
        stage_bf16(nb, s + 1);
      }
    }
    // compute from sm[cur]
    const unsigned short* Bsm = sm[cur] + 64 * 32;
    short8 af[4], bfr[4];
#pragma unroll
    for (int t = 0; t < 4; ++t) {
      af[t] = *(const short8*)&sm[cur][(t * 16 + lane15) * 32 + quad * 8];
      bfr[t] = *(const short8*)&Bsm[(wv * 64 + t * 16 + lane15) * 32 + quad * 8];
    }
#pragma unroll
    for (int mt = 0; mt < 4; ++mt)
#pragma unroll
      for (int nt = 0; nt < 4; ++nt)
        acc[mt][nt] = __builtin_amdgcn_mfma_f32_16x16x32_bf16(af[mt], bfr[nt],
                                                              acc[mt][nt], 0, 0, 0);
    // write-late A convert (loads had the MFMA phase to land)
    if (F32A && has_next) {
      __attribute__((aligned(16))) unsigned short o[8] = {
          f2bf(nf0.x), f2bf(nf0.y), f2bf(nf0.z), f2bf(nf0.w),
          f2bf(nf1.x), f2bf(nf1.y), f2bf(nf1.z), f2bf(nf1.w)};
      *(short8*)&sm[nb][ar_ * 32 + aks] = *(short8*)&o[0];
    }
    __syncthreads();
    cur = nb;
  }

  // epilogue
  float bsum[4];
#pragma unroll
  for (int nt = 0; nt < 4; ++nt) {
    int col = wv * 64 + nt * 16 + lane15;
    bsum[nt] = bias1[col] + (DUAL ? bias2[col] : 0.f);
  }
  float vv[4][4][4];
#pragma unroll
  for (int mt = 0; mt < 4; ++mt)
#pragma unroll
    for (int nt = 0; nt < 4; ++nt)
#pragma unroll
      for (int r = 0; r < 4; ++r)
        vv[mt][nt][r] = fmaxf(acc[mt][nt][r] + bsum[nt], 0.f);

  if (EPI == 0) {
#pragma unroll
    for (int mt = 0; mt < 4; ++mt)
#pragma unroll
      for (int r = 0; r < 4; ++r) {
        int row = bm + mt * 16 + quad * 4 + r;
        if (row < M) {
#pragma unroll
          for (int nt = 0; nt < 4; ++nt)
            Cb[(size_t)row * 256 + wv * 64 + nt * 16 + lane15] = f2bf(vv[mt][nt][r]);
        }
      }
    return;
  }

  // ---- LayerNorm over the full 256-col row ----
  float s1[4][4], s2[4][4];
#pragma unroll
  for (int mt = 0; mt < 4; ++mt)
#pragma unroll
    for (int r = 0; r < 4; ++r) {
      float a = 0.f, b = 0.f;
#pragma unroll
      for (int nt = 0; nt < 4; ++nt) {
        a += vv[mt][nt][r];
        b += vv[mt][nt][r] * vv[mt][nt][r];
      }
      s1[mt][r] = a;
      s2[mt][r] = b;
    }
#pragma unroll
  for (int st = 1; st < 16; st <<= 1)
#pragma unroll
    for (int mt = 0; mt < 4; ++mt)
#pragma unroll
      for (int r = 0; r < 4; ++r) {
        s1[mt][r] += __shfl_xor(s1[mt][r], st, 64);
        s2[mt][r] += __shfl_xor(s2[mt][r], st, 64);
      }
  if (lane15 == 0) {
#pragma unroll
    for (int mt = 0; mt < 4; ++mt)
#pragma unroll
      for (int r = 0; r < 4; ++r) {
        red1[wv][mt * 16 + quad * 4 + r] = s1[mt][r];
        red2[wv][mt * 16 + quad * 4 + r] = s2[mt][r];
      }
  }
  __syncthreads();
  if (tid < 64) {
    float a = red1[0][tid] + red1[1][tid] + red1[2][tid] + red1[3][tid];
    float b = red2[0][tid] + red2[1][tid] + red2[2][tid] + red2[3][tid];
    float mu = a * (1.f / 256.f);
    float var = fmaxf(b * (1.f / 256.f) - mu * mu, 0.f);
    mu_s[tid] = mu;
    rs_s[tid] = rsqrtf(var + 1e-5f);
  }
  __syncthreads();
  float gg[4], bb[4];
#pragma unroll
  for (int nt = 0; nt < 4; ++nt) {
    int col = wv * 64 + nt * 16 + lane15;
    gg[nt] = gamma[col];
    bb[nt] = beta[col];
  }
#pragma unroll
  for (int mt = 0; mt < 4; ++mt)
#pragma unroll
    for (int r = 0; r < 4; ++r) {
      int rowl = mt * 16 + quad * 4 + r;
      float mu = mu_s[rowl], rstd = rs_s[rowl];
#pragma unroll
      for (int nt = 0; nt < 4; ++nt)
        vv[mt][nt][r] = (vv[mt][nt][r] - mu) * rstd * gg[nt] + bb[nt];
    }

  if (EPI == 1) {
#pragma unroll
    for (int mt = 0; mt < 4; ++mt)
#pragma unroll
      for (int r = 0; r < 4; ++r) {
        int row = bm + mt * 16 + quad * 4 + r;
        if (row < M) {
#pragma unroll
          for (int nt = 0; nt < 4; ++nt)
            Cb[(size_t)row * 256 + wv * 64 + nt * 16 + lane15] = f2bf(vv[mt][nt][r]);
        }
      }
    return;
  }

  // ---- EPI==2: L2 normalize; store f32 Cf and bf16 Cb ----
  __syncthreads();
#pragma unroll
  for (int mt = 0; mt < 4; ++mt)
#pragma unroll
    for (int r = 0; r < 4; ++r) {
      float b = 0.f;
#pragma unroll
      for (int nt = 0; nt < 4; ++nt) b += vv[mt][nt][r] * vv[mt][nt][r];
      s2[mt][r] = b;
    }
#pragma unroll
  for (int st = 1; st < 16; st <<= 1)
#pragma unroll
    for (int mt = 0; mt < 4; ++mt)
#pragma unroll
      for (int r = 0; r < 4; ++r) s2[mt][r] += __shfl_xor(s2[mt][r], st, 64);
  if (lane15 == 0) {
#pragma unroll
    for (int mt = 0; mt < 4; ++mt)
#pragma unroll
      for (int r = 0; r < 4; ++r) red1[wv][mt * 16 + quad * 4 + r] = s2[mt][r];
  }
  __syncthreads();
  if (tid < 64) {
    float b = red1[0][tid] + red1[1][tid] + red1[2][tid] + red1[3][tid];
    mu_s[tid] = 1.f / fmaxf(sqrtf(b), 1e-12f);
  }
  __syncthreads();
#pragma unroll
  for (int mt = 0; mt < 4; ++mt)
#pragma unroll
    for (int r = 0; r < 4; ++r) {
      int rowl = mt * 16 + quad * 4 + r;
      int row = bm + rowl;
      float inv = mu_s[rowl];
      if (row < M) {
#pragma unroll
        for (int nt = 0; nt < 4; ++nt) {
          float y = vv[mt][nt][r] * inv;
          size_t idx = (size_t)row * 256 + wv * 64 + nt * 16 + lane15;
          Cf[idx] = y;
          Cb[idx] = f2bf(y);
        }
      }
    }
}

// ---------------- feat GEMM: single-read dual A-tile, double-buffered ------
__global__ __launch_bounds__(256) void feat_mfma_kernel(
    const unsigned short* __restrict__ Hb, const int* __restrict__ i_idx,
    const int* __restrict__ j_idx, const unsigned short* __restrict__ W1t,
    const float* __restrict__ b1, unsigned short* __restrict__ z1) {
  __shared__ __attribute__((aligned(16))) unsigned short Aabs[2][128 * 32];
  __shared__ __attribute__((aligned(16))) unsigned short Aprd[2][128 * 32];
  __shared__ __attribute__((aligned(16))) unsigned short Blo[2][128 * 32];
  __shared__ __attribute__((aligned(16))) unsigned short Bhi[2][128 * 32];  // 64KB total
  const int tid = threadIdx.x;
  const int wv = tid >> 6, ln = tid & 63;
  const int lane15 = ln & 15, quad = ln >> 4;
  const int mhalf = wv >> 1, nhalf = wv & 1;
  const int bm = blockIdx.x * 128;
  const int ar = tid >> 1;
  const int ak = (tid & 1) * 16;
  // per-thread pair index (ii/jj LDS dropped to fit 64KB double buffer)
  int ip = bm + ar;
  if (ip > PAIRS - 1) ip = PAIRS - 1;
  const unsigned short* __restrict__ hi_base = Hb + (size_t)i_idx[ip] * 256;
  const unsigned short* __restrict__ hj_base = Hb + (size_t)j_idx[ip] * 256;

  f32x4 acc[4][4] = {};

  auto stage_B = [&](int buf, int k0) {
#pragma unroll
    for (int q = 0; q < 2; ++q) {
      int L = q * 256 + tid;
      int r = L >> 2, ck = (L & 3) * 8;
      glds16(W1t + (size_t)r * 512 + k0 + ck,
             Blo[buf] + (size_t)(q * 256 + (tid & 192)) * 8);
      glds16(W1t + (size_t)r * 512 + 256 + k0 + ck,
             Bhi[buf] + (size_t)(q * 256 + (tid & 192)) * 8);
    }
  };

  union U { uint4 v; unsigned short s[8]; };
  auto conv_write = [&](int buf, U a0, U a1, U c0, U c1) {
    __attribute__((aligned(16))) unsigned short oabs[16], oprd[16];
#pragma unroll
    for (int e = 0; e < 8; ++e) {
      float x = bf2f(a0.s[e]), y = bf2f(c0.s[e]);
      oabs[e] = f2bf(fabsf(x - y));
      oprd[e] = f2bf(x * y);
    }
#pragma unroll
    for (int e = 0; e < 8; ++e) {
      float x = bf2f(a1.s[e]), y = bf2f(c1.s[e]);
      oabs[8 + e] = f2bf(fabsf(x - y));
      oprd[8 + e] = f2bf(x * y);
    }
    *(short8*)&Aabs[buf][ar * 32 + ak] = *(short8*)&oabs[0];
    *(short8*)&Aabs[buf][ar * 32 + ak + 8] = *(short8*)&oabs[8];
    *(short8*)&Aprd[buf][ar * 32 + ak] = *(short8*)&oprd[0];
    *(short8*)&Aprd[buf][ar * 32 + ak + 8] = *(short8*)&oprd[8];
  };

  // prologue: stage k-step 0 into buf 0
  {
    U a0, a1, c0, c1;
    a0.v = *(const uint4*)(hi_base + ak);
    a1.v = *(const uint4*)(hi_base + ak + 8);
    c0.v = *(const uint4*)(hj_base + ak);
    c1.v = *(const uint4*)(hj_base + ak + 8);
    stage_B(0, 0);
    conv_write(0, a0, a1, c0, c1);
  }
  __syncthreads();

  int cur = 0;
  for (int s = 0; s < 8; ++s) {
    const int nb = cur ^ 1;
    const bool has_next = (s < 7);
    U a0, a1, c0, c1;
    if (has_next) {
      int kn = (s + 1) * 32 + ak;
      a0.v = *(const uint4*)(hi_base + kn);
      a1.v = *(const uint4*)(hi_base + kn + 8);
      c0.v = *(const uint4*)(hj_base + kn);
      c1.v = *(const uint4*)(hj_base + kn + 8);
      stage_B(nb, (s + 1) * 32);
    }
    // compute from [cur]
    short8 aA[4], aP[4], bL[4], bH[4];
#pragma unroll
    for (int t = 0; t < 4; ++t) {
      int arow = (mhalf * 64 + t * 16 + lane15) * 32 + quad * 8;
      int brow = (nhalf * 64 + t * 16 + lane15) * 32 + quad * 8;
      aA[t] = *(const short8*)&Aabs[cur][arow];
      aP[t] = *(const short8*)&Aprd[cur][arow];
      bL[t] = *(const short8*)&Blo[cur][brow];
      bH[t] = *(const short8*)&Bhi[cur][brow];
    }
#pragma unroll
    for (int mt = 0; mt < 4; ++mt)
#pragma unroll
      for (int nt = 0; nt < 4; ++nt) {
        acc[mt][nt] = __builtin_amdgcn_mfma_f32_16x16x32_bf16(aA[mt], bL[nt],
                                                              acc[mt][nt], 0, 0, 0);
        acc[mt][nt] = __builtin_amdgcn_mfma_f32_16x16x32_bf16(aP[mt], bH[nt],
                                                              acc[mt][nt], 0, 0, 0);
      }
    // write-late A convert for next step
    if (has_next) conv_write(nb, a0, a1, c0, c1);
    __syncthreads();
    cur = nb;
  }

  float bsum[4];
#pragma unroll
  for (int nt = 0; nt < 4; ++nt) bsum[nt] = b1[nhalf * 64 + nt * 16 + lane15];
#pragma unroll
  for (int mt = 0; mt < 4; ++mt) {
    int rb = bm + mhalf * 64 + mt * 16 + quad * 4;
#pragma unroll
    for (int r = 0; r < 4; ++r) {
      int p = rb + r;
      if (p < PAIRS) {
#pragma unroll
        for (int nt = 0; nt < 4; ++nt) {
          float v = fmaxf(acc[mt][nt][r] + bsum[nt], 0.f);
          z1[(size_t)p * 128 + nhalf * 64 + nt * 16 + lane15] = f2bf(v);
        }
      }
    }
  }
}

// ---------------- z2 GEMM with fused logits, double-buffered ---------------
__global__ __launch_bounds__(256) void gemm_logits_kernel(
    const unsigned short* __restrict__ z1, const unsigned short* __restrict__ W2t,
    const float* __restrict__ b2, const float* __restrict__ W3,
    const float* __restrict__ b3, float* __restrict__ out) {
  __shared__ __attribute__((aligned(16))) unsigned short As[2][128 * 32];
  __shared__ __attribute__((aligned(16))) unsigned short Bs[2][128 * 32];
  __shared__ float red[2][128];
  const int tid = threadIdx.x;
  const int wv = tid >> 6, ln = tid & 63;
  const int lane15 = ln & 15, quad = ln >> 4;
  const int mhalf = wv >> 1, nhalf = wv & 1;
  const int bm = blockIdx.x * 128;
  f32x4 acc[4][4] = {};

  auto stageL = [&](int buf, int k0) {
#pragma unroll
    for (int q = 0; q < 2; ++q) {
      int L = (q * 4 + wv) * 64 + ln;
      int r = L >> 2, ck = (L & 3) * 8;
      int gr = bm + r;
      if (gr > PAIRS - 1) gr = PAIRS - 1;
      glds16(z1 + (size_t)gr * 128 + k0 + ck, As[buf] + (size_t)(q * 4 + wv) * 512);
      glds16(W2t + (size_t)r * 128 + k0 + ck, Bs[buf] + (size_t)(q * 4 + wv) * 512);
    }
  };

  stageL(0, 0);
  __syncthreads();

  int cur = 0;
  for (int s = 0; s < 4; ++s) {
    const int nb = cur ^ 1;
    if (s < 3) stageL(nb, (s + 1) * 32);
    short8 af[4], bfr[4];
#pragma unroll
    for (int t = 0; t < 4; ++t) {
      af[t] = *(const short8*)&As[cur][(mhalf * 64 + t * 16 + lane15) * 32 + quad * 8];
      bfr[t] = *(const short8*)&Bs[cur][(nhalf * 64 + t * 16 + lane15) * 32 + quad * 8];
    }
#pragma unroll
    for (int mt = 0; mt < 4; ++mt)
#pragma unroll
      for (int nt = 0; nt < 4; ++nt)
        acc[mt][nt] = __builtin_amdgcn_mfma_f32_16x16x32_bf16(af[mt], bfr[nt],
                                                              acc[mt][nt], 0, 0, 0);
    __syncthreads();
    cur = nb;
  }

  float bsum[4], w3v[4];
#pragma unroll
  for (int nt = 0; nt < 4; ++nt) {
    int col = nhalf * 64 + nt * 16 + lane15;
    bsum[nt] = b2[col];
    w3v[nt] = W3[col];
  }
  float p[4][4];
#pragma unroll
  for (int mt = 0; mt < 4; ++mt)
#pragma unroll
    for (int r = 0; r < 4; ++r) {
      float s = 0.f;
#pragma unroll
      for (int nt = 0; nt < 4; ++nt)
        s += fmaxf(acc[mt][nt][r] + bsum[nt], 0.f) * w3v[nt];
      p[mt][r] = s;
    }
#pragma unroll
  for (int st = 1; st < 16; st <<= 1)
#pragma unroll
    for (int mt = 0; mt < 4; ++mt)
#pragma unroll
      for (int r = 0; r < 4; ++r) p[mt][r] += __shfl_xor(p[mt][r], st, 64);
  if (lane15 == 0) {
#pragma unroll
    for (int mt = 0; mt < 4; ++mt)
#pragma unroll
      for (int r = 0; r < 4; ++r)
        red[nhalf][mhalf * 64 + mt * 16 + quad * 4 + r] = p[mt][r];
  }
  __syncthreads();
  if (tid < 128) {
    int prow = bm + tid;
    if (prow < PAIRS) out[prow] = red[0][tid] + red[1][tid] + b3[0];
  }
}

// ---------------- graph aggregate ----------------

__global__ __launch_bounds__(256) void aggregate_kernel(
    const unsigned short* __restrict__ h, const int* __restrict__ row_start,
    const int* __restrict__ csr, const float* __restrict__ degf,
    unsigned short* __restrict__ mean) {
  int wid = threadIdx.x >> 6, lane = threadIdx.x & 63;
  int n = blockIdx.x * 4 + wid;
  if (n >= NODES) return;
  int rs = row_start[n], re = row_start[n + 1];
  float a0 = 0.f, a1 = 0.f, a2 = 0.f, a3 = 0.f;
  int e = rs;
  for (; e + 2 <= re; e += 2) {
    int s0 = csr[e], s1 = csr[e + 1];
    ushort4 v0 = *(const ushort4*)(h + (size_t)s0 * 256 + lane * 4);
    ushort4 v1 = *(const ushort4*)(h + (size_t)s1 * 256 + lane * 4);
    a0 += bf2f(v0.x) + bf2f(v1.x);
    a1 += bf2f(v0.y) + bf2f(v1.y);
    a2 += bf2f(v0.z) + bf2f(v1.z);
    a3 += bf2f(v0.w) + bf2f(v1.w);
  }
  if (e < re) {
    ushort4 v0 = *(const ushort4*)(h + (size_t)csr[e] * 256 + lane * 4);
    a0 += bf2f(v0.x); a1 += bf2f(v0.y); a2 += bf2f(v0.z); a3 += bf2f(v0.w);
  }
  float inv = 1.0f / degf[n];
  ushort4 o = {f2bf(a0 * inv), f2bf(a1 * inv), f2bf(a2 * inv), f2bf(a3 * inv)};
  *(ushort4*)(mean + (size_t)n * 256 + lane * 4) = o;
}

// ---------------- host ----------------

extern "C" void kernel_launch(void* const* d_in, const int* in_sizes, int n_in,
                              void* d_out, int out_size, void* d_ws, size_t ws_size,
                              hipStream_t stream) {
  const float* X       = (const float*)d_in[0];
  const int*   edge    = (const int*)d_in[1];
  const int*   i_idx   = (const int*)d_in[2];
  const int*   j_idx   = (const int*)d_in[3];
  const float* W_in    = (const float*)d_in[4];
  const float* b_in    = (const float*)d_in[5];
  const float* Ws_self = (const float*)d_in[6];
  const float* bs_self = (const float*)d_in[7];
  const float* Ws_nei  = (const float*)d_in[8];
  const float* bs_nei  = (const float*)d_in[9];
  const float* gammas  = (const float*)d_in[10];
  const float* betas   = (const float*)d_in[11];
  const float* W1      = (const float*)d_in[12];
  const float* b1      = (const float*)d_in[13];
  const float* W2      = (const float*)d_in[14];
  const float* b2      = (const float*)d_in[15];
  const float* W3      = (const float*)d_in[16];
  const float* b3      = (const float*)d_in[17];

  char* w = (char*)d_ws;
  size_t off = 0;
  auto alloc = [&](size_t bytes) {
    char* p = w + off;
    off += (bytes + 255) & ~(size_t)255;
    return p;
  };
  unsigned short* hA   = (unsigned short*)alloc((size_t)NODES * 256 * 2);  // 25.6MB
  unsigned short* hB   = (unsigned short*)alloc((size_t)NODES * 256 * 2);
  unsigned short* mean = (unsigned short*)alloc((size_t)NODES * 256 * 2);
  unsigned short* Hb   = (unsigned short*)alloc((size_t)NODES * 256 * 2);
  float* degf     = (float*)alloc((size_t)NODES * 4);
  int* cnt        = (int*)alloc((size_t)2 * NODES * 4);
  int* cursor     = cnt + NODES;
  int* row_start  = (int*)alloc((size_t)(NODES + 1) * 4);
  int* csr        = (int*)alloc((size_t)EDGES * 4);
  int* bsum       = (int*)alloc((size_t)(SCAN_BLK + 1) * 4);
  int* boff       = (int*)alloc((size_t)(SCAN_BLK + 1) * 4);
  unsigned short* WinT   = (unsigned short*)alloc((size_t)480 * 256 * 2);
  unsigned short* WselfT = (unsigned short*)alloc((size_t)3 * 256 * 256 * 2);
  unsigned short* WneiT  = (unsigned short*)alloc((size_t)3 * 256 * 256 * 2);
  unsigned short* W1T    = (unsigned short*)alloc((size_t)512 * 128 * 2);
  unsigned short* W2T    = (unsigned short*)alloc((size_t)128 * 128 * 2);
  unsigned short* z1 = hA;  // reuse (hA/hB dead after layer 3)

  const int* src = edge;
  const int* dst = edge + EDGES;
  float* Hout   = (float*)d_out;
  float* logits = (float*)d_out + (size_t)NODES * 256;

  // weight conversions
  tconv_kernel<<<dim3(8, 15, 1), 256, 0, stream>>>(W_in, WinT, 480, 256);
  tconv_kernel<<<dim3(8, 8, 3), 256, 0, stream>>>(Ws_self, WselfT, 256, 256);
  tconv_kernel<<<dim3(8, 8, 3), 256, 0, stream>>>(Ws_nei, WneiT, 256, 256);
  tconv_kernel<<<dim3(4, 16, 1), 256, 0, stream>>>(W1, W1T, 512, 128);
  tconv_kernel<<<dim3(4, 4, 1), 256, 0, stream>>>(W2, W2T, 128, 128);

  // CSR build (hierarchical scan)
  hipMemsetAsync(cnt, 0, (size_t)2 * NODES * 4, stream);
  count_deg_kernel<<<(EDGES + 255) / 256, 256, 0, stream>>>(dst, cnt);
  blocksum_kernel<<<SCAN_BLK, 256, 0, stream>>>(cnt, bsum);
  scan_bsum_kernel<<<1, 64, 0, stream>>>(bsum, boff);
  scan_final_kernel<<<SCAN_BLK, 256, 0, stream>>>(cnt, boff, row_start, degf);
  fill_csr_kernel<<<(EDGES + 255) / 256, 256, 0, stream>>>(src, dst, row_start, cursor, csr);

  // encoder: hA = relu(X @ W_in + b_in), fp32 A staged in-kernel
  mfma_fused<0, 0, 1><<<782, 256, 0, stream>>>(
      nullptr, X, WinT, nullptr, nullptr, b_in, nullptr, nullptr, nullptr,
      hA, nullptr, NODES, 480);

  unsigned short* hcur = hA;
  unsigned short* hnext = hB;
  for (int l = 0; l < 3; ++l) {
    aggregate_kernel<<<NODES / 4, 256, 0, stream>>>(hcur, row_start, csr, degf, mean);
    if (l < 2) {
      mfma_fused<1, 1, 0><<<782, 256, 0, stream>>>(
          hcur, nullptr, WselfT + (size_t)l * 65536, mean, WneiT + (size_t)l * 65536,
          bs_self + l * 256, bs_nei + l * 256, gammas + l * 256, betas + l * 256,
          hnext, nullptr, NODES, 256);
      unsigned short* t = hcur; hcur = hnext; hnext = t;
    } else {
      mfma_fused<1, 2, 0><<<782, 256, 0, stream>>>(
          hcur, nullptr, WselfT + (size_t)l * 65536, mean, WneiT + (size_t)l * 65536,
          bs_self + l * 256, bs_nei + l * 256, gammas + l * 256, betas + l * 256,
          Hb, Hout, NODES, 256);
    }
  }

  // edge head
  feat_mfma_kernel<<<(PAIRS + 127) / 128, 256, 0, stream>>>(Hb, i_idx, j_idx, W1T, b1, z1);
  gemm_logits_kernel<<<(PAIRS + 127) / 128, 256, 0, stream>>>(z1, W2T, b2, W3, b3, logits);
}

// Round 3
// 552.061 us; speedup vs baseline: 1.0395x; 1.0395x over previous
//
#include <hip/hip_runtime.h>

// ---------------------------------------------------------------------------
// R6 = R5 resubmit (R5 bench died at container level; audit found no device-
// fault path). Changes vs R5: one sched_barrier(0) after the layer K-loop to
// pin epilogue vector loads below the counted-vmcnt region (insurance against
// LICM inflating vmcnt).
// R5: (a) feat_mfma reverted to R3 single-buffer (R4's 64KB dbuf cost 4->2
//     blocks/CU, 65->98us: TLP loss > pipeline gain on gather-latency kernel);
//     (b) layer mfma_fused -> depth-2 pipeline: 4 LDS buffers (80KB, epilogue
//     scratch aliased into buf0), raw s_barrier + counted s_waitcnt vmcnt(10)
//     so 2 tiles of glds16 stay in flight ACROSS the barrier (T4). Tail steps
//     wait 10->5->0. Encoder (F32A) keeps depth-1 (NBUF=2).
// Carried: hierarchical scan CSR, fused conv encoder, fused LN/L2norm/logits.
// ---------------------------------------------------------------------------

#define NODES 50000
#define EDGES 300000
#define PAIRS 200000
#define SCAN_BLK 49  // ceil(NODES/1024)

typedef __attribute__((ext_vector_type(8))) short short8;
typedef __attribute__((ext_vector_type(4))) float f32x4;

__device__ __forceinline__ unsigned short f2bf(float f) {
  unsigned int u = __float_as_uint(f);
  u += 0x7fff + ((u >> 16) & 1);
  return (unsigned short)(u >> 16);
}
__device__ __forceinline__ float bf2f(unsigned short h) {
  return __uint_as_float(((unsigned int)h) << 16);
}

__device__ __forceinline__ void glds16(const void* g, void* l) {
  __builtin_amdgcn_global_load_lds(
      (const __attribute__((address_space(1))) unsigned int*)g,
      (__attribute__((address_space(3))) unsigned int*)l, 16, 0, 0);
}

// ---------------- CSR build ----------------

__global__ __launch_bounds__(256) void count_deg_kernel(const int* __restrict__ dst,
                                                        int* __restrict__ cnt) {
  int e = blockIdx.x * 256 + threadIdx.x;
  if (e < EDGES) atomicAdd(&cnt[dst[e]], 1);
}

__global__ __launch_bounds__(256) void blocksum_kernel(const int* __restrict__ cnt,
                                                       int* __restrict__ bsum) {
  int base = blockIdx.x * 1024 + threadIdx.x * 4;
  int s = 0;
  if (base + 3 < NODES) {
    int4 v = *(const int4*)(cnt + base);
    s = v.x + v.y + v.z + v.w;
  } else {
#pragma unroll
    for (int k = 0; k < 4; ++k)
      if (base + k < NODES) s += cnt[base + k];
  }
#pragma unroll
  for (int off = 32; off; off >>= 1) s += __shfl_down(s, off);
  __shared__ int ws[4];
  if ((threadIdx.x & 63) == 0) ws[threadIdx.x >> 6] = s;
  __syncthreads();
  if (threadIdx.x == 0) bsum[blockIdx.x] = ws[0] + ws[1] + ws[2] + ws[3];
}

__global__ __launch_bounds__(64) void scan_bsum_kernel(const int* __restrict__ bsum,
                                                       int* __restrict__ boff) {
  int lane = threadIdx.x;
  int v = (lane < SCAN_BLK) ? bsum[lane] : 0;
  int incl = v;
#pragma unroll
  for (int off = 1; off < 64; off <<= 1) {
    int t = __shfl_up(incl, off);
    if (lane >= off) incl += t;
  }
  if (lane < SCAN_BLK) boff[lane] = incl - v;
}

__global__ __launch_bounds__(256) void scan_final_kernel(const int* __restrict__ cnt,
                                                         const int* __restrict__ boff,
                                                         int* __restrict__ row_start,
                                                         float* __restrict__ degf) {
  int base = blockIdx.x * 1024 + threadIdx.x * 4;
  int c[4] = {0, 0, 0, 0};
  if (base + 3 < NODES) {
    int4 v = *(const int4*)(cnt + base);
    c[0] = v.x; c[1] = v.y; c[2] = v.z; c[3] = v.w;
  } else {
#pragma unroll
    for (int k = 0; k < 4; ++k)
      if (base + k < NODES) c[k] = cnt[base + k];
  }
  int s = c[0] + c[1] + c[2] + c[3];
  int lane = threadIdx.x & 63, wv = threadIdx.x >> 6;
  int incl = s;
#pragma unroll
  for (int off = 1; off < 64; off <<= 1) {
    int t = __shfl_up(incl, off);
    if (lane >= off) incl += t;
  }
  __shared__ int wsum[4];
  if (lane == 63) wsum[wv] = incl;
  __syncthreads();
  int wbase = 0;
  for (int k = 0; k < wv; ++k) wbase += wsum[k];
  int rs = boff[blockIdx.x] + wbase + incl - s;
#pragma unroll
  for (int k = 0; k < 4; ++k) {
    int i = base + k;
    if (i < NODES) {
      row_start[i] = rs;
      degf[i] = (float)(c[k] > 0 ? c[k] : 1);
      rs += c[k];
    }
  }
  if (blockIdx.x == 0 && threadIdx.x == 0) row_start[NODES] = EDGES;
}

__global__ __launch_bounds__(256) void fill_csr_kernel(const int* __restrict__ src,
                                                       const int* __restrict__ dst,
                                                       const int* __restrict__ row_start,
                                                       int* __restrict__ cursor,
                                                       int* __restrict__ csr) {
  int e = blockIdx.x * 256 + threadIdx.x;
  if (e < EDGES) {
    int d = dst[e];
    int pos = atomicAdd(&cursor[d], 1);
    csr[row_start[d] + pos] = src[e];
  }
}

// ---------------- weight transpose+convert ----------------

__global__ __launch_bounds__(256) void tconv_kernel(const float* __restrict__ in,
                                                    unsigned short* __restrict__ out,
                                                    int R, int C) {
  const float* inb = in + (size_t)blockIdx.z * R * C;
  unsigned short* outb = out + (size_t)blockIdx.z * R * C;
  __shared__ float t[32][33];
  int bx = blockIdx.x * 32, by = blockIdx.y * 32;
  int tx = threadIdx.x & 31, ty = threadIdx.x >> 5;
#pragma unroll
  for (int i = ty; i < 32; i += 8) t[i][tx] = inb[(size_t)(by + i) * C + bx + tx];
  __syncthreads();
#pragma unroll
  for (int i = ty; i < 32; i += 8)
    outb[(size_t)(bx + i) * R + by + tx] = f2bf(t[tx][i]);
}

// ---------------- fused MFMA GEMM, N=256, BM=64 ----------------------------
// F32A: A read as fp32 with in-register bf16 convert (encoder; K=480), depth-1
// non-F32A (layers): depth-2 counted-vmcnt pipeline, 4 buffers
// EPI: 0 = relu->bf16; 1 = relu+LN->bf16; 2 = relu+LN+L2norm->f32+bf16
template <int DUAL, int EPI, int F32A>
__global__ __launch_bounds__(256) void mfma_fused(
    const unsigned short* __restrict__ A, const float* __restrict__ Af,
    const unsigned short* __restrict__ Bt,
    const unsigned short* __restrict__ A2, const unsigned short* __restrict__ B2t,
    const float* __restrict__ bias1, const float* __restrict__ bias2,
    const float* __restrict__ gamma, const float* __restrict__ beta,
    unsigned short* __restrict__ Cb, float* __restrict__ Cf, int M, int K) {
  constexpr int NBUF = F32A ? 2 : 4;
  __shared__ __attribute__((aligned(16))) unsigned short sm[NBUF][320 * 32];
  // epilogue scratch aliased into sm[0] (dead after K-loop; last-read tiles
  // land in sm[3]/sm[1] for NS=16, and max wave skew is 1 iteration)
  float* redbase = (float*)&sm[0][0];
  float* red1 = redbase;          // [4][64]
  float* red2 = redbase + 256;    // [4][64]
  float* mu_s = redbase + 512;    // [64]
  float* rs_s = redbase + 576;    // [64]
  const int tid = threadIdx.x;
  const int wv = tid >> 6, ln = tid & 63;
  const int lane15 = ln & 15, quad = ln >> 4;
  const int bm = blockIdx.x * 64;
  f32x4 acc[4][4] = {};

  const int ksteps = K >> 5;
  const int NS = ksteps * (DUAL + 1);

  // bf16-A staging: A(64x32) + B(256x32) via 5 glds16
  auto stage_bf16 = [&](int buf, int s) {
    int pass = 0, k0;
    if (DUAL && s >= ksteps) { pass = 1; k0 = (s - ksteps) * 32; }
    else { k0 = s * 32; }
    const unsigned short* __restrict__ Ap = pass ? A2 : A;
    const unsigned short* __restrict__ Bp = pass ? B2t : Bt;
#pragma unroll
    for (int q = 0; q < 5; ++q) {
      int L = q * 256 + tid;
      int r = L >> 2, ck = (L & 3) * 8;
      const unsigned short* gp;
      if (r < 64) {
        int gr = bm + r;
        if (gr > M - 1) gr = M - 1;
        gp = Ap + (size_t)gr * K + k0 + ck;
      } else {
        gp = Bp + (size_t)(r - 64) * K + k0 + ck;
      }
      glds16(gp, sm[buf] + (size_t)(q * 256 + (tid & 192)) * 8);
    }
  };
  // F32A: B-only staging (4 glds16); A handled via reg convert
  auto stage_B_f32a = [&](int buf, int k0) {
#pragma unroll
    for (int q = 1; q < 5; ++q) {
      int L = q * 256 + tid;
      int rr = L >> 2, ck = (L & 3) * 8;
      glds16(Bt + (size_t)(rr - 64) * K + k0 + ck,
             sm[buf] + (size_t)(q * 256 + (tid & 192)) * 8);
    }
  };

  auto compute_tile = [&](const unsigned short* smc) {
    const unsigned short* Bsm = smc + 64 * 32;
    short8 af[4], bfr[4];
#pragma unroll
    for (int t = 0; t < 4; ++t) {
      af[t] = *(const short8*)&smc[(t * 16 + lane15) * 32 + quad * 8];
      bfr[t] = *(const short8*)&Bsm[(wv * 64 + t * 16 + lane15) * 32 + quad * 8];
    }
#pragma unroll
    for (int mt = 0; mt < 4; ++mt)
#pragma unroll
      for (int nt = 0; nt < 4; ++nt)
        acc[mt][nt] = __builtin_amdgcn_mfma_f32_16x16x32_bf16(af[mt], bfr[nt],
                                                              acc[mt][nt], 0, 0, 0);
  };

  if (F32A) {
    // ---- depth-1 double-buffered (encoder) ----
    const int ar_ = tid >> 2, aks = (tid & 3) * 8;
    int agr = bm + ar_;
    if (agr > M - 1) agr = M - 1;
    const float* aRow = Af + (size_t)agr * K;

    {
      float4 f0 = *(const float4*)(aRow + aks);
      float4 f1 = *(const float4*)(aRow + aks + 4);
      stage_B_f32a(0, 0);
      __attribute__((aligned(16))) unsigned short o[8] = {
          f2bf(f0.x), f2bf(f0.y), f2bf(f0.z), f2bf(f0.w),
          f2bf(f1.x), f2bf(f1.y), f2bf(f1.z), f2bf(f1.w)};
      *(short8*)&sm[0][ar_ * 32 + aks] = *(short8*)&o[0];
    }
    __syncthreads();

    int cur = 0;
    for (int s = 0; s < NS; ++s) {
      const int nb = cur ^ 1;
      const bool has_next = (s + 1 < NS);
      float4 nf0, nf1;
      if (has_next) {
        int k0n = (s + 1) * 32;
        nf0 = *(const float4*)(aRow + k0n + aks);
        nf1 = *(const float4*)(aRow + k0n + aks + 4);
        stage_B_f32a(nb, k0n);
      }
      compute_tile(sm[cur]);
      if (has_next) {
        __attribute__((aligned(16))) unsigned short o[8] = {
            f2bf(nf0.x), f2bf(nf0.y), f2bf(nf0.z), f2bf(nf0.w),
            f2bf(nf1.x), f2bf(nf1.y), f2bf(nf1.z), f2bf(nf1.w)};
        *(short8*)&sm[nb][ar_ * 32 + aks] = *(short8*)&o[0];
      }
      __syncthreads();
      cur = nb;
    }
  } else {
    // ---- depth-2, 4 buffers, counted vmcnt, raw barriers (layers) ----
    stage_bf16(0, 0);
    if (NS > 1) stage_bf16(1, 1);
    for (int s = 0; s < NS; ++s) {
      if (s + 2 < NS) {
        stage_bf16((s + 2) & 3, s + 2);
        asm volatile("s_waitcnt vmcnt(10)" ::: "memory");  // tiles s+1,s+2 in flight
      } else if (s + 1 < NS) {
        asm volatile("s_waitcnt vmcnt(5)" ::: "memory");   // tile s+1 in flight
      } else {
        asm volatile("s_waitcnt vmcnt(0)" ::: "memory");
      }
      __builtin_amdgcn_sched_barrier(0);
      __builtin_amdgcn_s_barrier();
      __builtin_amdgcn_sched_barrier(0);
      compute_tile(sm[s & 3]);
    }
    __builtin_amdgcn_sched_barrier(0);  // keep epilogue vmem below the counted region
  }

  // epilogue
  float bsum[4];
#pragma unroll
  for (int nt = 0; nt < 4; ++nt) {
    int col = wv * 64 + nt * 16 + lane15;
    bsum[nt] = bias1[col] + (DUAL ? bias2[col] : 0.f);
  }
  float vv[4][4][4];
#pragma unroll
  for (int mt = 0; mt < 4; ++mt)
#pragma unroll
    for (int nt = 0; nt < 4; ++nt)
#pragma unroll
      for (int r = 0; r < 4; ++r)
        vv[mt][nt][r] = fmaxf(acc[mt][nt][r] + bsum[nt], 0.f);

  if (EPI == 0) {
#pragma unroll
    for (int mt = 0; mt < 4; ++mt)
#pragma unroll
      for (int r = 0; r < 4; ++r) {
        int row = bm + mt * 16 + quad * 4 + r;
        if (row < M) {
#pragma unroll
          for (int nt = 0; nt < 4; ++nt)
            Cb[(size_t)row * 256 + wv * 64 + nt * 16 + lane15] = f2bf(vv[mt][nt][r]);
        }
      }
    return;
  }

  // ---- LayerNorm over the full 256-col row ----
  float s1[4][4], s2[4][4];
#pragma unroll
  for (int mt = 0; mt < 4; ++mt)
#pragma unroll
    for (int r = 0; r < 4; ++r) {
      float a = 0.f, b = 0.f;
#pragma unroll
      for (int nt = 0; nt < 4; ++nt) {
        a += vv[mt][nt][r];
        b += vv[mt][nt][r] * vv[mt][nt][r];
      }
      s1[mt][r] = a;
      s2[mt][r] = b;
    }
#pragma unroll
  for (int st = 1; st < 16; st <<= 1)
#pragma unroll
    for (int mt = 0; mt < 4; ++mt)
#pragma unroll
      for (int r = 0; r < 4; ++r) {
        s1[mt][r] += __shfl_xor(s1[mt][r], st, 64);
        s2[mt][r] += __shfl_xor(s2[mt][r], st, 64);
      }
  if (lane15 == 0) {
#pragma unroll
    for (int mt = 0; mt < 4; ++mt)
#pragma unroll
      for (int r = 0; r < 4; ++r) {
        red1[wv * 64 + mt * 16 + quad * 4 + r] = s1[mt][r];
        red2[wv * 64 + mt * 16 + quad * 4 + r] = s2[mt][r];
      }
  }
  __syncthreads();
  if (tid < 64) {
    float a = red1[tid] + red1[64 + tid] + red1[128 + tid] + red1[192 + tid];
    float b = red2[tid] + red2[64 + tid] + red2[128 + tid] + red2[192 + tid];
    float mu = a * (1.f / 256.f);
    float var = fmaxf(b * (1.f / 256.f) - mu * mu, 0.f);
    mu_s[tid] = mu;
    rs_s[tid] = rsqrtf(var + 1e-5f);
  }
  __syncthreads();
  float gg[4], bb[4];
#pragma unroll
  for (int nt = 0; nt < 4; ++nt) {
    int col = wv * 64 + nt * 16 + lane15;
    gg[nt] = gamma[col];
    bb[nt] = beta[col];
  }
#pragma unroll
  for (int mt = 0; mt < 4; ++mt)
#pragma unroll
    for (int r = 0; r < 4; ++r) {
      int rowl = mt * 16 + quad * 4 + r;
      float mu = mu_s[rowl], rstd = rs_s[rowl];
#pragma unroll
      for (int nt = 0; nt < 4; ++nt)
        vv[mt][nt][r] = (vv[mt][nt][r] - mu) * rstd * gg[nt] + bb[nt];
    }

  if (EPI == 1) {
#pragma unroll
    for (int mt = 0; mt < 4; ++mt)
#pragma unroll
      for (int r = 0; r < 4; ++r) {
        int row = bm + mt * 16 + quad * 4 + r;
        if (row < M) {
#pragma unroll
          for (int nt = 0; nt < 4; ++nt)
            Cb[(size_t)row * 256 + wv * 64 + nt * 16 + lane15] = f2bf(vv[mt][nt][r]);
        }
      }
    return;
  }

  // ---- EPI==2: L2 normalize; store f32 Cf and bf16 Cb ----
  __syncthreads();
#pragma unroll
  for (int mt = 0; mt < 4; ++mt)
#pragma unroll
    for (int r = 0; r < 4; ++r) {
      float b = 0.f;
#pragma unroll
      for (int nt = 0; nt < 4; ++nt) b += vv[mt][nt][r] * vv[mt][nt][r];
      s2[mt][r] = b;
    }
#pragma unroll
  for (int st = 1; st < 16; st <<= 1)
#pragma unroll
    for (int mt = 0; mt < 4; ++mt)
#pragma unroll
      for (int r = 0; r < 4; ++r) s2[mt][r] += __shfl_xor(s2[mt][r], st, 64);
  if (lane15 == 0) {
#pragma unroll
    for (int mt = 0; mt < 4; ++mt)
#pragma unroll
      for (int r = 0; r < 4; ++r) red1[wv * 64 + mt * 16 + quad * 4 + r] = s2[mt][r];
  }
  __syncthreads();
  if (tid < 64) {
    float b = red1[tid] + red1[64 + tid] + red1[128 + tid] + red1[192 + tid];
    mu_s[tid] = 1.f / fmaxf(sqrtf(b), 1e-12f);
  }
  __syncthreads();
#pragma unroll
  for (int mt = 0; mt < 4; ++mt)
#pragma unroll
    for (int r = 0; r < 4; ++r) {
      int rowl = mt * 16 + quad * 4 + r;
      int row = bm + rowl;
      float inv = mu_s[rowl];
      if (row < M) {
#pragma unroll
        for (int nt = 0; nt < 4; ++nt) {
          float y = vv[mt][nt][r] * inv;
          size_t idx = (size_t)row * 256 + wv * 64 + nt * 16 + lane15;
          Cf[idx] = y;
          Cb[idx] = f2bf(y);
        }
      }
    }
}

// ---------------- feat GEMM: single-read dual A-tile (R3 version) ----------
__global__ __launch_bounds__(256) void feat_mfma_kernel(
    const unsigned short* __restrict__ Hb, const int* __restrict__ i_idx,
    const int* __restrict__ j_idx, const unsigned short* __restrict__ W1t,
    const float* __restrict__ b1, unsigned short* __restrict__ z1) {
  __shared__ __attribute__((aligned(16))) unsigned short Aabs[128 * 32];
  __shared__ __attribute__((aligned(16))) unsigned short Aprd[128 * 32];
  __shared__ __attribute__((aligned(16))) unsigned short Blo[128 * 32];
  __shared__ __attribute__((aligned(16))) unsigned short Bhi[128 * 32];
  __shared__ int ii[128], jj[128];
  const int tid = threadIdx.x;
  const int wv = tid >> 6, ln = tid & 63;
  const int lane15 = ln & 15, quad = ln >> 4;
  const int mhalf = wv >> 1, nhalf = wv & 1;
  const int bm = blockIdx.x * 128;
  if (tid < 128) {
    int p = bm + tid;
    if (p > PAIRS - 1) p = PAIRS - 1;
    ii[tid] = i_idx[p];
    jj[tid] = j_idx[p];
  }
  f32x4 acc[4][4] = {};
  const int ar = tid >> 1;
  const int ak = (tid & 1) * 16;

  for (int k0 = 0; k0 < 256; k0 += 32) {
    __syncthreads();
#pragma unroll
    for (int q = 0; q < 2; ++q) {
      int L = q * 256 + tid;
      int r = L >> 2, ck = (L & 3) * 8;
      glds16(W1t + (size_t)r * 512 + k0 + ck,
             Blo + (size_t)(q * 256 + (tid & 192)) * 8);
      glds16(W1t + (size_t)r * 512 + 256 + k0 + ck,
             Bhi + (size_t)(q * 256 + (tid & 192)) * 8);
    }
    {
      int kk = k0 + ak;
      const unsigned short* hi = Hb + (size_t)ii[ar] * 256 + kk;
      const unsigned short* hj = Hb + (size_t)jj[ar] * 256 + kk;
      union U { uint4 v; unsigned short s[8]; };
      U a0, a1, c0, c1;
      a0.v = *(const uint4*)(hi);
      a1.v = *(const uint4*)(hi + 8);
      c0.v = *(const uint4*)(hj);
      c1.v = *(const uint4*)(hj + 8);
      __attribute__((aligned(16))) unsigned short oabs[16], oprd[16];
#pragma unroll
      for (int e = 0; e < 8; ++e) {
        float x = bf2f(a0.s[e]), y = bf2f(c0.s[e]);
        oabs[e] = f2bf(fabsf(x - y));
        oprd[e] = f2bf(x * y);
      }
#pragma unroll
      for (int e = 0; e < 8; ++e) {
        float x = bf2f(a1.s[e]), y = bf2f(c1.s[e]);
        oabs[8 + e] = f2bf(fabsf(x - y));
        oprd[8 + e] = f2bf(x * y);
      }
      *(short8*)&Aabs[ar * 32 + ak] = *(short8*)&oabs[0];
      *(short8*)&Aabs[ar * 32 + ak + 8] = *(short8*)&oabs[8];
      *(short8*)&Aprd[ar * 32 + ak] = *(short8*)&oprd[0];
      *(short8*)&Aprd[ar * 32 + ak + 8] = *(short8*)&oprd[8];
    }
    __syncthreads();
    short8 aA[4], aP[4], bL[4], bH[4];
#pragma unroll
    for (int t = 0; t < 4; ++t) {
      int arow = (mhalf * 64 + t * 16 + lane15) * 32 + quad * 8;
      int brow = (nhalf * 64 + t * 16 + lane15) * 32 + quad * 8;
      aA[t] = *(const short8*)&Aabs[arow];
      aP[t] = *(const short8*)&Aprd[arow];
      bL[t] = *(const short8*)&Blo[brow];
      bH[t] = *(const short8*)&Bhi[brow];
    }
#pragma unroll
    for (int mt = 0; mt < 4; ++mt)
#pragma unroll
      for (int nt = 0; nt < 4; ++nt) {
        acc[mt][nt] = __builtin_amdgcn_mfma_f32_16x16x32_bf16(aA[mt], bL[nt],
                                                              acc[mt][nt], 0, 0, 0);
        acc[mt][nt] = __builtin_amdgcn_mfma_f32_16x16x32_bf16(aP[mt], bH[nt],
                                                              acc[mt][nt], 0, 0, 0);
      }
  }

  float bsum[4];
#pragma unroll
  for (int nt = 0; nt < 4; ++nt) bsum[nt] = b1[nhalf * 64 + nt * 16 + lane15];
#pragma unroll
  for (int mt = 0; mt < 4; ++mt) {
    int rb = bm + mhalf * 64 + mt * 16 + quad * 4;
#pragma unroll
    for (int r = 0; r < 4; ++r) {
      int p = rb + r;
      if (p < PAIRS) {
#pragma unroll
        for (int nt = 0; nt < 4; ++nt) {
          float v = fmaxf(acc[mt][nt][r] + bsum[nt], 0.f);
          z1[(size_t)p * 128 + nhalf * 64 + nt * 16 + lane15] = f2bf(v);
        }
      }
    }
  }
}

// ---------------- z2 GEMM with fused logits, double-buffered ---------------
__global__ __launch_bounds__(256) void gemm_logits_kernel(
    const unsigned short* __restrict__ z1, const unsigned short* __restrict__ W2t,
    const float* __restrict__ b2, const float* __restrict__ W3,
    const float* __restrict__ b3, float* __restrict__ out) {
  __shared__ __attribute__((aligned(16))) unsigned short As[2][128 * 32];
  __shared__ __attribute__((aligned(16))) unsigned short Bs[2][128 * 32];
  __shared__ float red[2][128];
  const int tid = threadIdx.x;
  const int wv = tid >> 6, ln = tid & 63;
  const int lane15 = ln & 15, quad = ln >> 4;
  const int mhalf = wv >> 1, nhalf = wv & 1;
  const int bm = blockIdx.x * 128;
  f32x4 acc[4][4] = {};

  auto stageL = [&](int buf, int k0) {
#pragma unroll
    for (int q = 0; q < 2; ++q) {
      int L = (q * 4 + wv) * 64 + ln;
      int r = L >> 2, ck = (L & 3) * 8;
      int gr = bm + r;
      if (gr > PAIRS - 1) gr = PAIRS - 1;
      glds16(z1 + (size_t)gr * 128 + k0 + ck, As[buf] + (size_t)(q * 4 + wv) * 512);
      glds16(W2t + (size_t)r * 128 + k0 + ck, Bs[buf] + (size_t)(q * 4 + wv) * 512);
    }
  };

  stageL(0, 0);
  __syncthreads();

  int cur = 0;
  for (int s = 0; s < 4; ++s) {
    const int nb = cur ^ 1;
    if (s < 3) stageL(nb, (s + 1) * 32);
    short8 af[4], bfr[4];
#pragma unroll
    for (int t = 0; t < 4; ++t) {
      af[t] = *(const short8*)&As[cur][(mhalf * 64 + t * 16 + lane15) * 32 + quad * 8];
      bfr[t] = *(const short8*)&Bs[cur][(nhalf * 64 + t * 16 + lane15) * 32 + quad * 8];
    }
#pragma unroll
    for (int mt = 0; mt < 4; ++mt)
#pragma unroll
      for (int nt = 0; nt < 4; ++nt)
        acc[mt][nt] = __builtin_amdgcn_mfma_f32_16x16x32_bf16(af[mt], bfr[nt],
                                                              acc[mt][nt], 0, 0, 0);
    __syncthreads();
    cur = nb;
  }

  float bsum[4], w3v[4];
#pragma unroll
  for (int nt = 0; nt < 4; ++nt) {
    int col = nhalf * 64 + nt * 16 + lane15;
    bsum[nt] = b2[col];
    w3v[nt] = W3[col];
  }
  float p[4][4];
#pragma unroll
  for (int mt = 0; mt < 4; ++mt)
#pragma unroll
    for (int r = 0; r < 4; ++r) {
      float s = 0.f;
#pragma unroll
      for (int nt = 0; nt < 4; ++nt)
        s += fmaxf(acc[mt][nt][r] + bsum[nt], 0.f) * w3v[nt];
      p[mt][r] = s;
    }
#pragma unroll
  for (int st = 1; st < 16; st <<= 1)
#pragma unroll
    for (int mt = 0; mt < 4; ++mt)
#pragma unroll
      for (int r = 0; r < 4; ++r) p[mt][r] += __shfl_xor(p[mt][r], st, 64);
  if (lane15 == 0) {
#pragma unroll
    for (int mt = 0; mt < 4; ++mt)
#pragma unroll
      for (int r = 0; r < 4; ++r)
        red[nhalf][mhalf * 64 + mt * 16 + quad * 4 + r] = p[mt][r];
  }
  __syncthreads();
  if (tid < 128) {
    int prow = bm + tid;
    if (prow < PAIRS) out[prow] = red[0][tid] + red[1][tid] + b3[0];
  }
}

// ---------------- graph aggregate ----------------

__global__ __launch_bounds__(256) void aggregate_kernel(
    const unsigned short* __restrict__ h, const int* __restrict__ row_start,
    const int* __restrict__ csr, const float* __restrict__ degf,
    unsigned short* __restrict__ mean) {
  int wid = threadIdx.x >> 6, lane = threadIdx.x & 63;
  int n = blockIdx.x * 4 + wid;
  if (n >= NODES) return;
  int rs = row_start[n], re = row_start[n + 1];
  float a0 = 0.f, a1 = 0.f, a2 = 0.f, a3 = 0.f;
  int e = rs;
  for (; e + 2 <= re; e += 2) {
    int s0 = csr[e], s1 = csr[e + 1];
    ushort4 v0 = *(const ushort4*)(h + (size_t)s0 * 256 + lane * 4);
    ushort4 v1 = *(const ushort4*)(h + (size_t)s1 * 256 + lane * 4);
    a0 += bf2f(v0.x) + bf2f(v1.x);
    a1 += bf2f(v0.y) + bf2f(v1.y);
    a2 += bf2f(v0.z) + bf2f(v1.z);
    a3 += bf2f(v0.w) + bf2f(v1.w);
  }
  if (e < re) {
    ushort4 v0 = *(const ushort4*)(h + (size_t)csr[e] * 256 + lane * 4);
    a0 += bf2f(v0.x); a1 += bf2f(v0.y); a2 += bf2f(v0.z); a3 += bf2f(v0.w);
  }
  float inv = 1.0f / degf[n];
  ushort4 o = {f2bf(a0 * inv), f2bf(a1 * inv), f2bf(a2 * inv), f2bf(a3 * inv)};
  *(ushort4*)(mean + (size_t)n * 256 + lane * 4) = o;
}

// ---------------- host ----------------

extern "C" void kernel_launch(void* const* d_in, const int* in_sizes, int n_in,
                              void* d_out, int out_size, void* d_ws, size_t ws_size,
                              hipStream_t stream) {
  const float* X       = (const float*)d_in[0];
  const int*   edge    = (const int*)d_in[1];
  const int*   i_idx   = (const int*)d_in[2];
  const int*   j_idx   = (const int*)d_in[3];
  const float* W_in    = (const float*)d_in[4];
  const float* b_in    = (const float*)d_in[5];
  const float* Ws_self = (const float*)d_in[6];
  const float* bs_self = (const float*)d_in[7];
  const float* Ws_nei  = (const float*)d_in[8];
  const float* bs_nei  = (const float*)d_in[9];
  const float* gammas  = (const float*)d_in[10];
  const float* betas   = (const float*)d_in[11];
  const float* W1      = (const float*)d_in[12];
  const float* b1      = (const float*)d_in[13];
  const float* W2      = (const float*)d_in[14];
  const float* b2      = (const float*)d_in[15];
  const float* W3      = (const float*)d_in[16];
  const float* b3      = (const float*)d_in[17];

  char* w = (char*)d_ws;
  size_t off = 0;
  auto alloc = [&](size_t bytes) {
    char* p = w + off;
    off += (bytes + 255) & ~(size_t)255;
    return p;
  };
  unsigned short* hA   = (unsigned short*)alloc((size_t)NODES * 256 * 2);  // 25.6MB
  unsigned short* hB   = (unsigned short*)alloc((size_t)NODES * 256 * 2);
  unsigned short* mean = (unsigned short*)alloc((size_t)NODES * 256 * 2);
  unsigned short* Hb   = (unsigned short*)alloc((size_t)NODES * 256 * 2);
  float* degf     = (float*)alloc((size_t)NODES * 4);
  int* cnt        = (int*)alloc((size_t)2 * NODES * 4);
  int* cursor     = cnt + NODES;
  int* row_start  = (int*)alloc((size_t)(NODES + 1) * 4);
  int* csr        = (int*)alloc((size_t)EDGES * 4);
  int* bsum       = (int*)alloc((size_t)(SCAN_BLK + 1) * 4);
  int* boff       = (int*)alloc((size_t)(SCAN_BLK + 1) * 4);
  unsigned short* WinT   = (unsigned short*)alloc((size_t)480 * 256 * 2);
  unsigned short* WselfT = (unsigned short*)alloc((size_t)3 * 256 * 256 * 2);
  unsigned short* WneiT  = (unsigned short*)alloc((size_t)3 * 256 * 256 * 2);
  unsigned short* W1T    = (unsigned short*)alloc((size_t)512 * 128 * 2);
  unsigned short* W2T    = (unsigned short*)alloc((size_t)128 * 128 * 2);
  unsigned short* z1 = hA;  // reuse (hA/hB dead after layer 3)

  const int* src = edge;
  const int* dst = edge + EDGES;
  float* Hout   = (float*)d_out;
  float* logits = (float*)d_out + (size_t)NODES * 256;

  // weight conversions
  tconv_kernel<<<dim3(8, 15, 1), 256, 0, stream>>>(W_in, WinT, 480, 256);
  tconv_kernel<<<dim3(8, 8, 3), 256, 0, stream>>>(Ws_self, WselfT, 256, 256);
  tconv_kernel<<<dim3(8, 8, 3), 256, 0, stream>>>(Ws_nei, WneiT, 256, 256);
  tconv_kernel<<<dim3(4, 16, 1), 256, 0, stream>>>(W1, W1T, 512, 128);
  tconv_kernel<<<dim3(4, 4, 1), 256, 0, stream>>>(W2, W2T, 128, 128);

  // CSR build (hierarchical scan)
  hipMemsetAsync(cnt, 0, (size_t)2 * NODES * 4, stream);
  count_deg_kernel<<<(EDGES + 255) / 256, 256, 0, stream>>>(dst, cnt);
  blocksum_kernel<<<SCAN_BLK, 256, 0, stream>>>(cnt, bsum);
  scan_bsum_kernel<<<1, 64, 0, stream>>>(bsum, boff);
  scan_final_kernel<<<SCAN_BLK, 256, 0, stream>>>(cnt, boff, row_start, degf);
  fill_csr_kernel<<<(EDGES + 255) / 256, 256, 0, stream>>>(src, dst, row_start, cursor, csr);

  // encoder: hA = relu(X @ W_in + b_in), fp32 A staged in-kernel
  mfma_fused<0, 0, 1><<<782, 256, 0, stream>>>(
      nullptr, X, WinT, nullptr, nullptr, b_in, nullptr, nullptr, nullptr,
      hA, nullptr, NODES, 480);

  unsigned short* hcur = hA;
  unsigned short* hnext = hB;
  for (int l = 0; l < 3; ++l) {
    aggregate_kernel<<<NODES / 4, 256, 0, stream>>>(hcur, row_start, csr, degf, mean);
    if (l < 2) {
      mfma_fused<1, 1, 0><<<782, 256, 0, stream>>>(
          hcur, nullptr, WselfT + (size_t)l * 65536, mean, WneiT + (size_t)l * 65536,
          bs_self + l * 256, bs_nei + l * 256, gammas + l * 256, betas + l * 256,
          hnext, nullptr, NODES, 256);
      unsigned short* t = hcur; hcur = hnext; hnext = t;
    } else {
      mfma_fused<1, 2, 0><<<782, 256, 0, stream>>>(
          hcur, nullptr, WselfT + (size_t)l * 65536, mean, WneiT + (size_t)l * 65536,
          bs_self + l * 256, bs_nei + l * 256, gammas + l * 256, betas + l * 256,
          Hb, Hout, NODES, 256);
    }
  }

  // edge head
  feat_mfma_kernel<<<(PAIRS + 127) / 128, 256, 0, stream>>>(Hb, i_idx, j_idx, W1T, b1, z1);
  gemm_logits_kernel<<<(PAIRS + 127) / 128, 256, 0, stream>>>(z1, W2T, b2, W3, b3, logits);
}